// Round 9
// baseline (125.611 us; speedup 1.0000x reference)
//
#include <hip/hip_runtime.h>
#include <hip/hip_bf16.h>
#include <cstdint>

using f32x4  = __attribute__((ext_vector_type(4))) float;
using bf16x8 = __attribute__((ext_vector_type(8))) short;
typedef unsigned short u16;

#define B_DIM 64
#define N_DIM 1024
#define P_DIM 256
#define NTILE 8              // N / 128
#define NUPPER 36            // NTILE*(NTILE+1)/2
#define NB_PREP 16384        // (B*N)/4
#define NB_GRAM 9216         // B * NUPPER * 4 wave-tasks (divisible by 8)

// RNE float->bf16
__device__ __forceinline__ u16 f2bf(float f) {
  uint32_t u = __float_as_uint(f);
  u += 0x7fffu + ((u >> 16) & 1u);
  return (u16)(u >> 16);
}

// ---------------------------------------------------------------------------
// Kernel 1: fused BCE partial + per-row sumsq + fp32->bf16 cast. (~HBM/L3 floor)
// ---------------------------------------------------------------------------
__global__ __launch_bounds__(256) void prep_kernel(
    const float* __restrict__ X, const float* __restrict__ T,
    u16* __restrict__ Xbf, float* __restrict__ sq,
    float* __restrict__ pb) {
  int tid  = threadIdx.x;
  int w    = tid >> 6, lane = tid & 63;
  size_t row = (size_t)blockIdx.x * 4 + w;
  const float4 xv = ((const float4*)(X + row * P_DIM))[lane];
  const float4 tv = ((const float4*)(T + row * P_DIM))[lane];
  float xs[4] = {xv.x, xv.y, xv.z, xv.w};
  float ts[4] = {tv.x, tv.y, tv.z, tv.w};
  float sqp = 0.f, bce = 0.f;
  ushort4 us;
  u16* up = (u16*)&us;
  #pragma unroll
  for (int i = 0; i < 4; ++i) {
    float x = xs[i];
    sqp += x * x;
    bce += fmaxf(x, 0.f) - x * ts[i] + __logf(1.f + __expf(-fabsf(x)));
    up[i] = f2bf(x);
  }
  ((ushort4*)(Xbf + row * P_DIM))[lane] = us;
  #pragma unroll
  for (int off = 32; off; off >>= 1) {
    sqp += __shfl_down(sqp, off);
    bce += __shfl_down(bce, off);
  }
  __shared__ float red[4];
  if (lane == 0) { sq[row] = sqp; red[w] = bce; }
  __syncthreads();
  if (tid == 0)
    pb[blockIdx.x] = red[0] + red[1] + red[2] + red[3];
}

// ---------------------------------------------------------------------------
// Kernel 2 (R9): ZERO-LDS register-direct Gram. One wave = one 64x64 tile.
// Insight: the 16x16x32 bf16 fragment layout (lane holds 8 CONTIGUOUS
// K-elements of row lane&15, k-slot lane>>4) is directly loadable from the
// row-major bf16 array with ONE global_load_dwordx4 per fragment — 64 lanes
// touch 16 fully-consumed 64B L2 lines (not R3's 16B scatter). Data is
// L2-resident (FETCH=16.6MB, R5-R8). So the whole dataflow is
// global->reg->MFMA: no ds_write/ds_read/lgkm chains, no barriers, no LDS.
// Per K-step: 8 loads (immediate offsets off precomputed per-m/n base ptrs)
// + 16 MFMA. R8 post-mortem: all LDS variants were issue/latency-bound at
// ~30% packing; this removes the serial LDS round-trip entirely.
// ---------------------------------------------------------------------------
__global__ __launch_bounds__(64) void gram_kernel(
    const u16* __restrict__ Xbf, const float* __restrict__ sq,
    float* __restrict__ pd) {
  // XCD-aware swizzle (NB_GRAM % 8 == 0): XCD x gets 1152 consecutive
  // logical ids = 8 batches -> panel set fits one L2.
  int p   = blockIdx.x;
  int gid = (p & 7) * (NB_GRAM / 8) + (p >> 3);
  int b   = gid / (NUPPER * 4);
  int r   = gid - b * (NUPPER * 4);
  int pr  = r >> 2;                     // tile-pair 0..35
  int wv  = r & 3;                      // wave slot within pair
  int TI  = 0, t = pr;
  while (t >= NTILE - TI) { t -= NTILE - TI; ++TI; }
  int TJ = TI + t;                      // TJ >= TI
  int wr = wv >> 1, wc = wv & 1;
  const bool diag = (TI == TJ);
  if (diag && wr > wc) {                // dead sub-tile: fully below diagonal
    if (threadIdx.x == 0) pd[p] = 0.f;
    return;
  }

  const u16*   Xb  = Xbf + (size_t)b * N_DIM * P_DIM;
  const float* sqb = sq + b * N_DIM;

  const int lane = threadIdx.x;         // 64 threads = 1 wave
  const int rowA = TI * 128 + wr * 64;
  const int rowB = TJ * 128 + wc * 64;
  const bool same = (rowA == rowB);     // diag (0,0)/(1,1): B tile == A tile

  // Fragment base pointers: lane reads row fr=lane&15 (+16m), 16B k-slot
  // ksl=lane>>4. Per-step offset = k*32 u16 = k*64B -> load immediate.
  const int fr = lane & 15, ksl = lane >> 4;
  const u16* pA0 = Xb + (size_t)(rowA + fr) * P_DIM + ksl * 8;
  const u16* pA1 = pA0 + 16 * P_DIM;
  const u16* pA2 = pA0 + 32 * P_DIM;
  const u16* pA3 = pA0 + 48 * P_DIM;
  const u16* pB0 = Xb + (size_t)(rowB + fr) * P_DIM + ksl * 8;
  const u16* pB1 = pB0 + 16 * P_DIM;
  const u16* pB2 = pB0 + 32 * P_DIM;
  const u16* pB3 = pB0 + 48 * P_DIM;

  f32x4 acc[4][4];
  #pragma unroll
  for (int m = 0; m < 4; ++m)
    #pragma unroll
    for (int n = 0; n < 4; ++n)
      acc[m][n] = (f32x4)(0.f);

  #pragma unroll
  for (int k = 0; k < 8; ++k) {
    const int off = k * 32;             // u16 elements = k*64 bytes
    bf16x8 a0 = *(const bf16x8*)(pA0 + off);
    bf16x8 a1 = *(const bf16x8*)(pA1 + off);
    bf16x8 a2 = *(const bf16x8*)(pA2 + off);
    bf16x8 a3 = *(const bf16x8*)(pA3 + off);
    bf16x8 b0, b1, b2, b3;
    if (!same) {
      b0 = *(const bf16x8*)(pB0 + off);
      b1 = *(const bf16x8*)(pB1 + off);
      b2 = *(const bf16x8*)(pB2 + off);
      b3 = *(const bf16x8*)(pB3 + off);
    } else {
      b0 = a0; b1 = a1; b2 = a2; b3 = a3;
    }
    acc[0][0] = __builtin_amdgcn_mfma_f32_16x16x32_bf16(a0, b0, acc[0][0], 0, 0, 0);
    acc[0][1] = __builtin_amdgcn_mfma_f32_16x16x32_bf16(a0, b1, acc[0][1], 0, 0, 0);
    acc[0][2] = __builtin_amdgcn_mfma_f32_16x16x32_bf16(a0, b2, acc[0][2], 0, 0, 0);
    acc[0][3] = __builtin_amdgcn_mfma_f32_16x16x32_bf16(a0, b3, acc[0][3], 0, 0, 0);
    acc[1][0] = __builtin_amdgcn_mfma_f32_16x16x32_bf16(a1, b0, acc[1][0], 0, 0, 0);
    acc[1][1] = __builtin_amdgcn_mfma_f32_16x16x32_bf16(a1, b1, acc[1][1], 0, 0, 0);
    acc[1][2] = __builtin_amdgcn_mfma_f32_16x16x32_bf16(a1, b2, acc[1][2], 0, 0, 0);
    acc[1][3] = __builtin_amdgcn_mfma_f32_16x16x32_bf16(a1, b3, acc[1][3], 0, 0, 0);
    acc[2][0] = __builtin_amdgcn_mfma_f32_16x16x32_bf16(a2, b0, acc[2][0], 0, 0, 0);
    acc[2][1] = __builtin_amdgcn_mfma_f32_16x16x32_bf16(a2, b1, acc[2][1], 0, 0, 0);
    acc[2][2] = __builtin_amdgcn_mfma_f32_16x16x32_bf16(a2, b2, acc[2][2], 0, 0, 0);
    acc[2][3] = __builtin_amdgcn_mfma_f32_16x16x32_bf16(a2, b3, acc[2][3], 0, 0, 0);
    acc[3][0] = __builtin_amdgcn_mfma_f32_16x16x32_bf16(a3, b0, acc[3][0], 0, 0, 0);
    acc[3][1] = __builtin_amdgcn_mfma_f32_16x16x32_bf16(a3, b1, acc[3][1], 0, 0, 0);
    acc[3][2] = __builtin_amdgcn_mfma_f32_16x16x32_bf16(a3, b2, acc[3][2], 0, 0, 0);
    acc[3][3] = __builtin_amdgcn_mfma_f32_16x16x32_bf16(a3, b3, acc[3][3], 0, 0, 0);
  }

  // Epilogue: C layout (m89/m91): col = lane&15, row = (lane>>4)*4 + v.
  float sqa[16], sqc[4];
  {
    int rb2 = rowA + (lane >> 4) * 4;
    int cb  = rowB + (lane & 15);
    #pragma unroll
    for (int m = 0; m < 4; ++m)
      #pragma unroll
      for (int v = 0; v < 4; ++v)
        sqa[m * 4 + v] = sqb[rb2 + m * 16 + v];
    #pragma unroll
    for (int n = 0; n < 4; ++n)
      sqc[n] = sqb[cb + n * 16];
  }
  float ssum = 0.f;
  #pragma unroll
  for (int m = 0; m < 4; ++m) {
    #pragma unroll
    for (int n = 0; n < 4; ++n) {
      #pragma unroll
      for (int v = 0; v < 4; ++v) {
        float d2 = sqa[m * 4 + v] + sqc[n] - 2.f * acc[m][n][v];
        float d  = sqrtf(fmaxf(d2, 0.f));
        if (same) {
          int li = m * 16 + (lane >> 4) * 4 + v;   // local row
          int lj = n * 16 + (lane & 15);           // local col
          d = (li < lj) ? d : 0.f;
        }
        ssum += d;
      }
    }
  }
  #pragma unroll
  for (int off = 32; off; off >>= 1) ssum += __shfl_down(ssum, off);
  if (lane == 0) pd[p] = ssum;
}

// ---------------------------------------------------------------------------
// Kernel 3: reduce partials (double) and combine.
// ---------------------------------------------------------------------------
__global__ __launch_bounds__(256) void finalize_kernel(
    const float* __restrict__ pb, const float* __restrict__ pd,
    float* __restrict__ out) {
  int tid = threadIdx.x;
  double s = 0.0, d = 0.0;
  for (int i = tid; i < NB_PREP; i += 256) s += (double)pb[i];
  for (int i = tid; i < NB_GRAM; i += 256) d += (double)pd[i];
  #pragma unroll
  for (int off = 32; off; off >>= 1) {
    s += __shfl_down(s, off);
    d += __shfl_down(d, off);
  }
  __shared__ double sb[4], db[4];
  int w = tid >> 6, lane = tid & 63;
  if (lane == 0) { sb[w] = s; db[w] = d; }
  __syncthreads();
  if (tid == 0) {
    double bce = (sb[0] + sb[1] + sb[2] + sb[3]) /
                 (double)((size_t)B_DIM * N_DIM * P_DIM);
    double reg = (db[0] + db[1] + db[2] + db[3]) / (double)N_DIM;
    out[0] = (float)(bce - reg);
  }
}

extern "C" void kernel_launch(void* const* d_in, const int* in_sizes, int n_in,
                              void* d_out, int out_size, void* d_ws, size_t ws_size,
                              hipStream_t stream) {
  const float* X = (const float*)d_in[0];
  const float* T = (const float*)d_in[1];
  float* out = (float*)d_out;

  // ws layout:
  //   [0, 64KB)        pb  — per-block BCE partials (16384 f32)
  //   [64KB, 100KB)    pd  — per-wave dist partials (9216 f32)
  //   [112KB, 368KB)   sq  — per-row sum of squares (65536 f32)
  //   [384KB, ~34MB)   Xbf — bf16 copy of X
  float* pb  = (float*)d_ws;
  float* pd  = (float*)((char*)d_ws + (64 << 10));
  float* sq  = (float*)((char*)d_ws + (112 << 10));
  u16*   Xbf = (u16*)  ((char*)d_ws + (384 << 10));

  prep_kernel<<<NB_PREP, 256, 0, stream>>>(X, T, Xbf, sq, pb);
  gram_kernel<<<NB_GRAM, 64, 0, stream>>>(Xbf, sq, pd);
  finalize_kernel<<<1, 256, 0, stream>>>(pb, pd, out);
}